// Round 8
// baseline (16383.928 us; speedup 1.0000x reference)
//
#include <hip/hip_runtime.h>
#include <math.h>

#define BATCH 2048
#define SEQ   128
#define HID   512
#define OUTT  24
#define RPB   16              // batch rows per pair (MFMA M)
#define NBLK  256             // 2 blocks per row-group (N-split halves)
#define TPB   512             // 8 waves
#define KTN   16              // k-tiles (K=32 each)
#define NTILES 32
#define SLAB  16384           // elements per kt slab in packed B

typedef _Float16 half8 __attribute__((ext_vector_type(8)));
typedef float   floatx4 __attribute__((ext_vector_type(4)));

// fast tanh: 1 - 2/(e^{2x}+1); saturates correctly at +-inf
__device__ __forceinline__ float ftanh(float x) {
    float e = __builtin_amdgcn_exp2f(x * 2.885390081777927f);
    float r = __builtin_amdgcn_rcpf(e + 1.0f);
    return fmaf(-2.0f, r, 1.0f);
}

// Pack W[j][k] (row-major HIDxHID fp32) into per-lane MFMA B-fragment layout (fp16):
// frag[(kt*32+nt)*64 + lane][8]; lane holds B[k=kt*32+(lane>>4)*8+jj][n=nt*16+(lane&15)].
__global__ __launch_bounds__(256) void pack_wfrag(const float* __restrict__ W,
                                                  _Float16* __restrict__ Bw)
{
    int id   = blockIdx.x * 256 + threadIdx.x;
    int lane = id & 63;
    int nt   = (id >> 6) & 31;
    int kt   = id >> 11;
    int n  = nt * 16 + (lane & 15);
    int k0 = kt * 32 + (lane >> 4) * 8;
    const float* src = W + (size_t)n * HID + k0;
    half8 v;
    #pragma unroll
    for (int j = 0; j < 8; j++) v[j] = (_Float16)src[j];
    *(half8*)&Bw[(size_t)id * 8] = v;
}

// Swizzled A layout: el(m,k) = (k>>5)*512 + G*128 + ((m^G)<<3) + (k&7), G=(k>>3)&3.
// Reader lane (q,c) reads k-tile kt contiguously at kt*512 + q*128 + ((c^q)<<3).
// kt-major => own n-half [s*256, s*256+256) occupies contiguous LDS [s*4096, +4096).
__global__ __launch_bounds__(TPB, 2) void rnn_persist(
    const float* __restrict__ x,
    const _Float16* __restrict__ BwE,
    const _Float16* __restrict__ BwD,
    const float* __restrict__ encWih, const float* __restrict__ encBih,
    const float* __restrict__ encBhh,
    const float* __restrict__ decWih, const float* __restrict__ decBih,
    const float* __restrict__ decBhh,
    const float* __restrict__ fcW, const float* __restrict__ fcB,
    _Float16* __restrict__ xbuf,    // exchange: [blk][parity][hi 4096 | lo 4096]
    int* __restrict__ flags,        // per-block step counter (memset 0 each launch)
    float* __restrict__ out)
{
    __shared__ _Float16 Ahi[2][KTN * 512];   // 32 KB
    __shared__ _Float16 Alo[2][KTN * 512];   // 32 KB
    __shared__ float    xs[RPB][SEQ];        // 8 KB
    __shared__ float    fws[HID];            // 2 KB
    __shared__ float    dec_in_s[RPB];
    __shared__ float    pad[1800];           // force LDS > 80 KiB => 1 block/CU

    const int tid  = threadIdx.x;
    const int lane = tid & 63;
    const int wv   = tid >> 6;
    const int bid  = blockIdx.x;
    const int s    = bid & 1;                // n-half
    const int row0 = (bid >> 1) * RPB;
    const int c    = lane & 15;
    const int q    = lane >> 4;
    const int mB   = q * 4;
    if (out == nullptr) pad[tid] = 0.f;      // opaque guard keeps pad allocated

    const int nt0 = s * 16 + wv * 2;         // this wave's 2 n-tiles (absolute)

    float eWi[2], eBb[2], dWi[2], dBb[2];
    #pragma unroll
    for (int i = 0; i < 2; i++) {
        int n = (nt0 + i) * 16 + c;
        eWi[i] = encWih[n]; eBb[i] = encBih[n] + encBhh[n];
        dWi[i] = decWih[n]; dBb[i] = decBih[n] + decBhh[n];
    }
    const float fcb0 = fcB[0];

    // preload x rows and fcW
    ((float4*)&xs[0][0])[tid] = ((const float4*)(x + (size_t)row0 * SEQ))[tid];
    if (tid < HID) fws[tid] = fcW[tid];

    // h0 = 0 (both halves)
    for (int i = tid; i < KTN * 512 / 2; i += TPB) {
        ((int*)Ahi[0])[i] = 0;
        ((int*)Alo[0])[i] = 0;
    }
    __syncthreads();

    const int ldsAoff = q * 128 + ((c ^ q) << 3);
    const size_t bb = ((size_t)nt0 * 64 + lane) * 8;

    int cur = 0;
    floatx4 acc0, acc1;

    for (int t = 0; t < SEQ + OUTT; t++) {
        const bool enc = (t < SEQ);
        const _Float16* __restrict__ Bw = enc ? BwE : BwD;
        const _Float16* Ah = Ahi[cur];
        const _Float16* Al = Alo[cur];

        acc0 = (floatx4){0.f, 0.f, 0.f, 0.f};
        acc1 = (floatx4){0.f, 0.f, 0.f, 0.f};

        // 8-kt GEMM chunk with 3-deep rolling B prefetch
        auto gemm8 = [&](int kb) {
            half8 b0a = *(const half8*)&Bw[(size_t)(kb + 0) * SLAB + bb];
            half8 b0b = *(const half8*)&Bw[(size_t)(kb + 0) * SLAB + bb + 512];
            half8 b1a = *(const half8*)&Bw[(size_t)(kb + 1) * SLAB + bb];
            half8 b1b = *(const half8*)&Bw[(size_t)(kb + 1) * SLAB + bb + 512];
            half8 b2a = *(const half8*)&Bw[(size_t)(kb + 2) * SLAB + bb];
            half8 b2b = *(const half8*)&Bw[(size_t)(kb + 2) * SLAB + bb + 512];
            #pragma unroll
            for (int kk = 0; kk < 8; kk++) {
                const int kt = kb + kk;
                half8 ah = *(const half8*)&Ah[kt * 512 + ldsAoff];
                half8 al = *(const half8*)&Al[kt * 512 + ldsAoff];
                half8 na, nb;
                if (kk + 3 < 8) {
                    na = *(const half8*)&Bw[(size_t)(kt + 3) * SLAB + bb];
                    nb = *(const half8*)&Bw[(size_t)(kt + 3) * SLAB + bb + 512];
                }
                acc0 = __builtin_amdgcn_mfma_f32_16x16x32_f16(ah, b0a, acc0, 0, 0, 0);
                acc0 = __builtin_amdgcn_mfma_f32_16x16x32_f16(al, b0a, acc0, 0, 0, 0);
                acc1 = __builtin_amdgcn_mfma_f32_16x16x32_f16(ah, b0b, acc1, 0, 0, 0);
                acc1 = __builtin_amdgcn_mfma_f32_16x16x32_f16(al, b0b, acc1, 0, 0, 0);
                b0a = b1a; b0b = b1b; b1a = b2a; b1b = b2b;
                if (kk + 3 < 8) { b2a = na; b2b = nb; }
            }
        };

        // FC over full h in LDS[cur]; writes dec_in_s (+ out if s==0)
        auto fc_full = [&](int outIdx) {
            #pragma unroll
            for (int rr = 0; rr < 2; rr++) {
                int m = wv * 2 + rr;
                float sm = 0.f;
                #pragma unroll
                for (int ii = 0; ii < HID / 64; ii++) {
                    int k = ii * 64 + lane;
                    int G = (k >> 3) & 3;
                    int a = (k >> 5) * 512 + G * 128 + ((m ^ G) << 3) + (k & 7);
                    sm = fmaf((float)Ahi[cur][a] + (float)Alo[cur][a], fws[k], sm);
                }
                #pragma unroll
                for (int off = 32; off > 0; off >>= 1)
                    sm += __shfl_down(sm, off, 64);
                if (lane == 0) {
                    float o = sm + fcb0;
                    dec_in_s[m] = o;
                    if (s == 0) out[(size_t)(row0 + m) * OUTT + outIdx] = o;
                }
            }
        };

        // (1) GEMM over OWN-half k-tiles (no partner data needed)
        gemm8(s * 8);

        // (2) exchange-in: partner's half of h_t (posted at its step t-1)
        if (t > 0) {
            if (tid == 0) {
                while (__hip_atomic_load(&flags[bid ^ 1], __ATOMIC_ACQUIRE,
                                         __HIP_MEMORY_SCOPE_AGENT) < t)
                    __builtin_amdgcn_s_sleep(2);
            }
            __syncthreads();
            __threadfence();
            const int par = t & 1;
            const _Float16* pb = xbuf + ((size_t)(bid ^ 1) * 2 + par) * 8192;
            *(half8*)&Ahi[cur][(1 - s) * 4096 + tid * 8] = *(const half8*)&pb[tid * 8];
            *(half8*)&Alo[cur][(1 - s) * 4096 + tid * 8] = *(const half8*)&pb[4096 + tid * 8];
        }
        __syncthreads();

        // (2.5) deferred decoder FC: LDS[cur] now holds FULL h_t
        if (t > SEQ) {
            fc_full(t - 1 - SEQ);
            __syncthreads();
        }

        // (3) GEMM over PARTNER-half k-tiles
        gemm8((1 - s) * 8);

        // (4) epilogue -> LDS[nxt] own half
        float inp[4];
        if (enc) {
            #pragma unroll
            for (int r = 0; r < 4; r++) inp[r] = xs[mB + r][t];
        } else if (t == SEQ) {
            #pragma unroll
            for (int r = 0; r < 4; r++) inp[r] = xs[mB + r][SEQ - 1];
        } else {
            #pragma unroll
            for (int r = 0; r < 4; r++) inp[r] = dec_in_s[mB + r];
        }

        const int nxt = cur ^ 1;
        #pragma unroll
        for (int i = 0; i < 2; i++) {
            floatx4 a = i ? acc1 : acc0;
            int k = (nt0 + i) * 16 + c;      // this n is next step's k
            int G = (k >> 3) & 3;
            int base = (k >> 5) * 512 + G * 128 + (k & 7);
            float wi = enc ? eWi[i] : dWi[i];
            float bo = enc ? eBb[i] : dBb[i];
            #pragma unroll
            for (int r = 0; r < 4; r++) {
                float v = ftanh(a[r] + inp[r] * wi + bo);
                _Float16 hh = (_Float16)v;
                float rs = v - (float)hh;
                int off = base + (((mB + r) ^ G) << 3);
                Ahi[nxt][off] = hh;
                Alo[nxt][off] = (_Float16)rs;
            }
        }
        __syncthreads();   // own half of LDS[nxt] complete

        // (5) exchange-out: publish own half of h_{t+1}
        {
            const int par = (t + 1) & 1;
            _Float16* xb = xbuf + ((size_t)bid * 2 + par) * 8192;
            *(half8*)&xb[tid * 8]        = *(const half8*)&Ahi[nxt][s * 4096 + tid * 8];
            *(half8*)&xb[4096 + tid * 8] = *(const half8*)&Alo[nxt][s * 4096 + tid * 8];
        }
        __threadfence();
        __syncthreads();
        if (tid == 0)
            __hip_atomic_store(&flags[bid], t + 1, __ATOMIC_RELEASE,
                               __HIP_MEMORY_SCOPE_AGENT);
        cur = nxt;
    }

    // final FC: needs full h_{SEQ+OUTT}
    {
        const int tEnd = SEQ + OUTT;
        if (tid == 0) {
            while (__hip_atomic_load(&flags[bid ^ 1], __ATOMIC_ACQUIRE,
                                     __HIP_MEMORY_SCOPE_AGENT) < tEnd)
                __builtin_amdgcn_s_sleep(2);
        }
        __syncthreads();
        __threadfence();
        const int par = tEnd & 1;
        const _Float16* pb = xbuf + ((size_t)(bid ^ 1) * 2 + par) * 8192;
        *(half8*)&Ahi[cur][(1 - s) * 4096 + tid * 8] = *(const half8*)&pb[tid * 8];
        *(half8*)&Alo[cur][(1 - s) * 4096 + tid * 8] = *(const half8*)&pb[4096 + tid * 8];
        __syncthreads();

        #pragma unroll
        for (int rr = 0; rr < 2; rr++) {
            int m = wv * 2 + rr;
            float sm = 0.f;
            #pragma unroll
            for (int ii = 0; ii < HID / 64; ii++) {
                int k = ii * 64 + lane;
                int G = (k >> 3) & 3;
                int a = (k >> 5) * 512 + G * 128 + ((m ^ G) << 3) + (k & 7);
                sm = fmaf((float)Ahi[cur][a] + (float)Alo[cur][a], fws[k], sm);
            }
            #pragma unroll
            for (int off = 32; off > 0; off >>= 1)
                sm += __shfl_down(sm, off, 64);
            if (lane == 0 && s == 0)
                out[(size_t)(row0 + m) * OUTT + (OUTT - 1)] = sm + fcb0;
        }
    }
}

extern "C" void kernel_launch(void* const* d_in, const int* in_sizes, int n_in,
                              void* d_out, int out_size, void* d_ws, size_t ws_size,
                              hipStream_t stream)
{
    const float* x        = (const float*)d_in[0];
    const float* enc_Wih  = (const float*)d_in[1];
    const float* enc_Whh  = (const float*)d_in[2];
    const float* enc_bih  = (const float*)d_in[3];
    const float* enc_bhh  = (const float*)d_in[4];
    const float* dec_Wih  = (const float*)d_in[5];
    const float* dec_Whh  = (const float*)d_in[6];
    const float* dec_bih  = (const float*)d_in[7];
    const float* dec_bhh  = (const float*)d_in[8];
    const float* fc_W     = (const float*)d_in[9];
    const float* fc_b     = (const float*)d_in[10];
    float* out = (float*)d_out;

    const size_t wfrag = (size_t)HID * HID;          // 262144 halves = 512 KB
    _Float16* BwE  = (_Float16*)d_ws;
    _Float16* BwD  = BwE + wfrag;
    _Float16* xbuf = BwD + wfrag;                    // 256 blk * 2 par * 8192 = 8 MB
    int* flags = (int*)(xbuf + (size_t)NBLK * 2 * 8192);

    hipMemsetAsync(flags, 0, NBLK * sizeof(int), stream);
    pack_wfrag<<<HID * HID / (256 * 8), 256, 0, stream>>>(enc_Whh, BwE);
    pack_wfrag<<<HID * HID / (256 * 8), 256, 0, stream>>>(dec_Whh, BwD);

    rnn_persist<<<NBLK, TPB, 0, stream>>>(
        x, BwE, BwD,
        enc_Wih, enc_bih, enc_bhh,
        dec_Wih, dec_bih, dec_bhh,
        fc_W, fc_b, xbuf, flags, out);
}

// Round 9
// 811.287 us; speedup vs baseline: 20.1950x; 20.1950x over previous
//
#include <hip/hip_runtime.h>
#include <math.h>

#define BATCH 2048
#define SEQ   128
#define HID   512
#define OUTT  24
#define RPB   16              // batch rows per block (MFMA M)
#define NBLK  (BATCH/RPB)     // 128 blocks
#define TPB   512             // 8 waves = 2/SIMD
#define NTW   4               // n-tiles per wave
#define KTN   16              // k-tiles (K=32)
#define SLAB  16384           // elements per kt slab in packed B
#define QD    4               // B prefetch queue depth (3 kt ahead)

typedef _Float16 half8 __attribute__((ext_vector_type(8)));
typedef float   floatx4 __attribute__((ext_vector_type(4)));

// fast tanh: 1 - 2/(e^{2x}+1); saturates correctly
__device__ __forceinline__ float ftanh(float x) {
    float e = __builtin_amdgcn_exp2f(x * 2.885390081777927f);
    float r = __builtin_amdgcn_rcpf(e + 1.0f);
    return fmaf(-2.0f, r, 1.0f);
}

// Pack W[j][k] (row-major HIDxHID fp32) -> per-lane MFMA B-fragment fp16:
// frag[(kt*32+nt)*64 + lane][8]; lane holds B[k=kt*32+(lane>>4)*8+jj][n=nt*16+(lane&15)].
__global__ __launch_bounds__(256) void pack_wfrag(const float* __restrict__ W,
                                                  _Float16* __restrict__ Bw)
{
    int id   = blockIdx.x * 256 + threadIdx.x;
    int lane = id & 63;
    int nt   = (id >> 6) & 31;
    int kt   = id >> 11;
    int n  = nt * 16 + (lane & 15);
    int k0 = kt * 32 + (lane >> 4) * 8;
    const float* src = W + (size_t)n * HID + k0;
    half8 v;
    #pragma unroll
    for (int j = 0; j < 8; j++) v[j] = (_Float16)src[j];
    *(half8*)&Bw[(size_t)id * 8] = v;
}

// Swizzled A layout: el(m,k) = (k>>5)*512 + G*128 + ((m^G)<<3) + (k&7), G=(k>>3)&3.
// Reader lane (q,c) reads k-tile kt as one contiguous 16 B at kt*512 + q*128 + ((c^q)<<3).
__global__ __launch_bounds__(TPB, 2) void rnn_persist(
    const float* __restrict__ x,
    const _Float16* __restrict__ BwE,
    const _Float16* __restrict__ BwD,
    const float* __restrict__ encWih, const float* __restrict__ encBih,
    const float* __restrict__ encBhh,
    const float* __restrict__ decWih, const float* __restrict__ decBih,
    const float* __restrict__ decBhh,
    const float* __restrict__ fcW, const float* __restrict__ fcB,
    float* __restrict__ out)
{
    __shared__ _Float16 Ahi[2][KTN * 512];   // 32 KB ping-pong
    __shared__ _Float16 Alo[2][KTN * 512];   // 32 KB
    __shared__ float    xs[RPB][SEQ];        // 8 KB
    __shared__ float    dec_in_s[RPB];

    const int tid  = threadIdx.x;
    const int lane = tid & 63;
    const int wv   = tid >> 6;
    const int row0 = blockIdx.x * RPB;
    const int c    = lane & 15;
    const int q    = lane >> 4;
    const int mB   = q * 4;
    const int nt0  = wv * NTW;

    // hoisted epilogue constants (per owned n)
    float eWi[NTW], eBb[NTW], dWi[NTW], dBb[NTW];
    #pragma unroll
    for (int i = 0; i < NTW; i++) {
        int n = (nt0 + i) * 16 + c;
        eWi[i] = encWih[n]; eBb[i] = encBih[n] + encBhh[n];
        dWi[i] = decWih[n]; dBb[i] = decBih[n] + decBhh[n];
    }
    const float fcb0 = fcB[0];

    // preload x rows (coalesced float4)
    ((float4*)&xs[0][0])[tid] = ((const float4*)(x + (size_t)row0 * SEQ))[tid];

    // h0 = 0
    for (int i = tid; i < KTN * 512 / 2; i += TPB) {
        ((int*)Ahi[0])[i] = 0;
        ((int*)Alo[0])[i] = 0;
    }
    __syncthreads();

    const int ldsAoff = q * 128 + ((c ^ q) << 3);
    const size_t bb = ((size_t)nt0 * 512 + (size_t)lane * 8);

    int cur = 0;
    for (int t = 0; t < SEQ + OUTT; t++) {
        const bool enc = (t < SEQ);
        const _Float16* __restrict__ Bw = enc ? BwE : BwD;
        const _Float16* Ah = Ahi[cur];
        const _Float16* Al = Alo[cur];

        floatx4 acc[NTW];
        #pragma unroll
        for (int i = 0; i < NTW; i++) acc[i] = (floatx4){0.f, 0.f, 0.f, 0.f};

        // ---- K-loop: depth-4 rolling B prefetch (12 loads in flight) ----
        half8 Bq[QD][NTW];
        #pragma unroll
        for (int d = 0; d < QD - 1; d++)
            #pragma unroll
            for (int i = 0; i < NTW; i++)
                Bq[d][i] = *(const half8*)&Bw[(size_t)d * SLAB + bb + i * 512];

        #pragma unroll
        for (int kt = 0; kt < KTN; kt++) {
            if (kt + QD - 1 < KTN) {
                const int ps = (kt + QD - 1) & (QD - 1);
                #pragma unroll
                for (int i = 0; i < NTW; i++)
                    Bq[ps][i] = *(const half8*)&Bw[(size_t)(kt + QD - 1) * SLAB + bb + i * 512];
            }
            const int slot = kt & (QD - 1);
            half8 ah = *(const half8*)&Ah[kt * 512 + ldsAoff];
            half8 al = *(const half8*)&Al[kt * 512 + ldsAoff];
            #pragma unroll
            for (int i = 0; i < NTW; i++)
                acc[i] = __builtin_amdgcn_mfma_f32_16x16x32_f16(ah, Bq[slot][i], acc[i], 0, 0, 0);
            #pragma unroll
            for (int i = 0; i < NTW; i++)
                acc[i] = __builtin_amdgcn_mfma_f32_16x16x32_f16(al, Bq[slot][i], acc[i], 0, 0, 0);
        }

        // ---- epilogue ----
        float inp[4];
        if (enc) {
            #pragma unroll
            for (int r = 0; r < 4; r++) inp[r] = xs[mB + r][t];
        } else if (t == SEQ) {
            #pragma unroll
            for (int r = 0; r < 4; r++) inp[r] = xs[mB + r][SEQ - 1];
        } else {
            #pragma unroll
            for (int r = 0; r < 4; r++) inp[r] = dec_in_s[mB + r];
        }

        const int nxt = cur ^ 1;
        #pragma unroll
        for (int i = 0; i < NTW; i++) {
            int k = (nt0 + i) * 16 + c;      // this n is next step's k
            int G = (k >> 3) & 3;
            int base = (k >> 5) * 512 + G * 128 + (k & 7);
            float wi = enc ? eWi[i] : dWi[i];
            float bo = enc ? eBb[i] : dBb[i];
            #pragma unroll
            for (int r = 0; r < 4; r++) {
                float v = ftanh(acc[i][r] + inp[r] * wi + bo);
                _Float16 hh = (_Float16)v;
                float rs = v - (float)hh;
                int off = base + (((mB + r) ^ G) << 3);
                Ahi[nxt][off] = hh;
                Alo[nxt][off] = (_Float16)rs;
            }
        }
        __syncthreads();   // A[nxt] complete

        if (!enc) {
            // FC: wave wv reduces rows 2wv, 2wv+1 from A[nxt]
            #pragma unroll
            for (int rr = 0; rr < 2; rr++) {
                int m = wv * 2 + rr;
                float s = 0.f;
                #pragma unroll
                for (int ii = 0; ii < HID / 64; ii++) {
                    int k = ii * 64 + lane;
                    int G = (k >> 3) & 3;
                    int a = (k >> 5) * 512 + G * 128 + ((m ^ G) << 3) + (k & 7);
                    s = fmaf((float)Ahi[nxt][a] + (float)Alo[nxt][a], fcW[k], s);
                }
                #pragma unroll
                for (int off = 32; off > 0; off >>= 1)
                    s += __shfl_down(s, off, 64);
                if (lane == 0) {
                    float o = s + fcb0;
                    dec_in_s[m] = o;
                    out[(size_t)(row0 + m) * OUTT + (t - SEQ)] = o;
                }
            }
            __syncthreads();
        }
        cur = nxt;
    }
}

extern "C" void kernel_launch(void* const* d_in, const int* in_sizes, int n_in,
                              void* d_out, int out_size, void* d_ws, size_t ws_size,
                              hipStream_t stream)
{
    const float* x        = (const float*)d_in[0];
    const float* enc_Wih  = (const float*)d_in[1];
    const float* enc_Whh  = (const float*)d_in[2];
    const float* enc_bih  = (const float*)d_in[3];
    const float* enc_bhh  = (const float*)d_in[4];
    const float* dec_Wih  = (const float*)d_in[5];
    const float* dec_Whh  = (const float*)d_in[6];
    const float* dec_bih  = (const float*)d_in[7];
    const float* dec_bhh  = (const float*)d_in[8];
    const float* fc_W     = (const float*)d_in[9];
    const float* fc_b     = (const float*)d_in[10];
    float* out = (float*)d_out;

    const size_t wfrag = (size_t)HID * HID;
    _Float16* BwE = (_Float16*)d_ws;
    _Float16* BwD = BwE + wfrag;

    pack_wfrag<<<HID * HID / (256 * 8), 256, 0, stream>>>(enc_Whh, BwE);
    pack_wfrag<<<HID * HID / (256 * 8), 256, 0, stream>>>(dec_Whh, BwD);

    rnn_persist<<<NBLK, TPB, 0, stream>>>(
        x, BwE, BwD,
        enc_Wih, enc_bih, enc_bhh,
        dec_Wih, dec_bih, dec_bhh,
        fc_W, fc_b, out);
}

// Round 10
// 749.447 us; speedup vs baseline: 21.8614x; 1.0825x over previous
//
#include <hip/hip_runtime.h>
#include <math.h>

#define BATCH 2048
#define SEQ   128
#define HID   512
#define OUTT  24
#define RPB   16              // batch rows per block (MFMA M)
#define NBLK  (BATCH/RPB)     // 128 blocks
#define TPB   1024            // 16 waves = 4/SIMD
#define NWV   16
#define NTW   2               // n-tiles per wave
#define KTN   16              // k-tiles (K=32)
#define SLAB  16384           // elements per kt slab in packed B
#define QD    4               // B prefetch queue depth (3 kt ahead)

typedef _Float16 half8 __attribute__((ext_vector_type(8)));
typedef float   floatx4 __attribute__((ext_vector_type(4)));

// fast tanh: 1 - 2/(e^{2x}+1); saturates correctly
__device__ __forceinline__ float ftanh(float x) {
    float e = __builtin_amdgcn_exp2f(x * 2.885390081777927f);
    float r = __builtin_amdgcn_rcpf(e + 1.0f);
    return fmaf(-2.0f, r, 1.0f);
}

// Pack W[j][k] (row-major HIDxHID fp32) -> per-lane MFMA B-fragment fp16:
// frag[(kt*32+nt)*64 + lane][8]; lane holds B[k=kt*32+(lane>>4)*8+jj][n=nt*16+(lane&15)].
__global__ __launch_bounds__(256) void pack_wfrag(const float* __restrict__ W,
                                                  _Float16* __restrict__ Bw)
{
    int id   = blockIdx.x * 256 + threadIdx.x;
    int lane = id & 63;
    int nt   = (id >> 6) & 31;
    int kt   = id >> 11;
    int n  = nt * 16 + (lane & 15);
    int k0 = kt * 32 + (lane >> 4) * 8;
    const float* src = W + (size_t)n * HID + k0;
    half8 v;
    #pragma unroll
    for (int j = 0; j < 8; j++) v[j] = (_Float16)src[j];
    *(half8*)&Bw[(size_t)id * 8] = v;
}

// Swizzled A layout: el(m,k) = (k>>5)*512 + G*128 + ((m^G)<<3) + (k&7), G=(k>>3)&3.
// Reader lane (q,c) reads k-tile kt as one contiguous 16 B at kt*512 + q*128 + ((c^q)<<3).
__global__ __launch_bounds__(TPB, 1) void rnn_persist(
    const float* __restrict__ x,
    const _Float16* __restrict__ BwE,
    const _Float16* __restrict__ BwD,
    const float* __restrict__ encWih, const float* __restrict__ encBih,
    const float* __restrict__ encBhh,
    const float* __restrict__ decWih, const float* __restrict__ decBih,
    const float* __restrict__ decBhh,
    const float* __restrict__ fcW, const float* __restrict__ fcB,
    float* __restrict__ out)
{
    __shared__ _Float16 Ahi[2][KTN * 512];   // 32 KB ping-pong
    __shared__ _Float16 Alo[2][KTN * 512];   // 32 KB
    __shared__ float    xs[RPB][SEQ];        // 8 KB
    __shared__ float    dec_in_s[RPB];

    const int tid  = threadIdx.x;
    const int lane = tid & 63;
    const int wv   = tid >> 6;               // 0..15
    const int row0 = blockIdx.x * RPB;
    const int c    = lane & 15;
    const int q    = lane >> 4;
    const int mB   = q * 4;
    const int nt0  = wv * NTW;

    // hoisted epilogue constants (per owned n)
    float eWi[NTW], eBb[NTW], dWi[NTW], dBb[NTW];
    #pragma unroll
    for (int i = 0; i < NTW; i++) {
        int n = (nt0 + i) * 16 + c;
        eWi[i] = encWih[n]; eBb[i] = encBih[n] + encBhh[n];
        dWi[i] = decWih[n]; dBb[i] = decBih[n] + decBhh[n];
    }
    const float fcb0 = fcB[0];

    // preload x rows (coalesced float4)
    if (tid < RPB * SEQ / 4)
        ((float4*)&xs[0][0])[tid] = ((const float4*)(x + (size_t)row0 * SEQ))[tid];

    // h0 = 0
    for (int i = tid; i < KTN * 512 / 2; i += TPB) {
        ((int*)Ahi[0])[i] = 0;
        ((int*)Alo[0])[i] = 0;
    }
    __syncthreads();

    const int ldsAoff = q * 128 + ((c ^ q) << 3);
    const size_t bb = ((size_t)nt0 * 512 + (size_t)lane * 8);

    // ---- prime rolling B queue for t=0 (kt 0..2 of encoder) ----
    half8 Bq[QD][NTW];
    #pragma unroll
    for (int d = 0; d < QD - 1; d++)
        #pragma unroll
        for (int i = 0; i < NTW; i++)
            Bq[d][i] = *(const half8*)&BwE[(size_t)d * SLAB + bb + i * 512];

    int cur = 0;
    for (int t = 0; t < SEQ + OUTT; t++) {
        const bool enc = (t < SEQ);
        const _Float16* __restrict__ Bw  = enc ? BwE : BwD;
        const _Float16* __restrict__ Bwn = (t + 1 < SEQ) ? BwE : BwD;
        const _Float16* Ah = Ahi[cur];
        const _Float16* Al = Alo[cur];

        floatx4 acc[NTW];
        #pragma unroll
        for (int i = 0; i < NTW; i++) acc[i] = (floatx4){0.f, 0.f, 0.f, 0.f};

        // ---- K-loop; prefetch rolls past the end into next step's kt 0..2 ----
        #pragma unroll
        for (int kt = 0; kt < KTN; kt++) {
            const int pf = kt + QD - 1;
            const int ps = pf & (QD - 1);
            if (pf < KTN) {
                #pragma unroll
                for (int i = 0; i < NTW; i++)
                    Bq[ps][i] = *(const half8*)&Bw[(size_t)pf * SLAB + bb + i * 512];
            } else {
                #pragma unroll
                for (int i = 0; i < NTW; i++)
                    Bq[ps][i] = *(const half8*)&Bwn[(size_t)(pf - KTN) * SLAB + bb + i * 512];
            }
            const int slot = kt & (QD - 1);
            half8 ah = *(const half8*)&Ah[kt * 512 + ldsAoff];
            half8 al = *(const half8*)&Al[kt * 512 + ldsAoff];
            #pragma unroll
            for (int i = 0; i < NTW; i++)
                acc[i] = __builtin_amdgcn_mfma_f32_16x16x32_f16(ah, Bq[slot][i], acc[i], 0, 0, 0);
            #pragma unroll
            for (int i = 0; i < NTW; i++)
                acc[i] = __builtin_amdgcn_mfma_f32_16x16x32_f16(al, Bq[slot][i], acc[i], 0, 0, 0);
        }

        // ---- epilogue ----
        float inp[4];
        if (enc) {
            #pragma unroll
            for (int r = 0; r < 4; r++) inp[r] = xs[mB + r][t];
        } else if (t == SEQ) {
            #pragma unroll
            for (int r = 0; r < 4; r++) inp[r] = xs[mB + r][SEQ - 1];
        } else {
            #pragma unroll
            for (int r = 0; r < 4; r++) inp[r] = dec_in_s[mB + r];
        }

        const int nxt = cur ^ 1;
        #pragma unroll
        for (int i = 0; i < NTW; i++) {
            int k = (nt0 + i) * 16 + c;      // this n is next step's k
            int G = (k >> 3) & 3;
            int base = (k >> 5) * 512 + G * 128 + (k & 7);
            float wi = enc ? eWi[i] : dWi[i];
            float bo = enc ? eBb[i] : dBb[i];
            #pragma unroll
            for (int r = 0; r < 4; r++) {
                float v = ftanh(acc[i][r] + inp[r] * wi + bo);
                _Float16 hh = (_Float16)v;
                float rs = v - (float)hh;
                int off = base + (((mB + r) ^ G) << 3);
                Ahi[nxt][off] = hh;
                Alo[nxt][off] = (_Float16)rs;
            }
        }
        __syncthreads();   // A[nxt] complete

        if (!enc) {
            // FC: wave wv reduces row wv (16 waves, 16 rows)
            const int m = wv;
            float s = 0.f;
            #pragma unroll
            for (int ii = 0; ii < HID / 64; ii++) {
                int k = ii * 64 + lane;
                int G = (k >> 3) & 3;
                int a = (k >> 5) * 512 + G * 128 + ((m ^ G) << 3) + (k & 7);
                s = fmaf((float)Ahi[nxt][a] + (float)Alo[nxt][a], fcW[k], s);
            }
            #pragma unroll
            for (int off = 32; off > 0; off >>= 1)
                s += __shfl_down(s, off, 64);
            if (lane == 0) {
                float o = s + fcb0;
                dec_in_s[m] = o;
                out[(size_t)(row0 + m) * OUTT + (t - SEQ)] = o;
            }
            __syncthreads();
        }
        cur = nxt;
    }
}

extern "C" void kernel_launch(void* const* d_in, const int* in_sizes, int n_in,
                              void* d_out, int out_size, void* d_ws, size_t ws_size,
                              hipStream_t stream)
{
    const float* x        = (const float*)d_in[0];
    const float* enc_Wih  = (const float*)d_in[1];
    const float* enc_Whh  = (const float*)d_in[2];
    const float* enc_bih  = (const float*)d_in[3];
    const float* enc_bhh  = (const float*)d_in[4];
    const float* dec_Wih  = (const float*)d_in[5];
    const float* dec_Whh  = (const float*)d_in[6];
    const float* dec_bih  = (const float*)d_in[7];
    const float* dec_bhh  = (const float*)d_in[8];
    const float* fc_W     = (const float*)d_in[9];
    const float* fc_b     = (const float*)d_in[10];
    float* out = (float*)d_out;

    const size_t wfrag = (size_t)HID * HID;
    _Float16* BwE = (_Float16*)d_ws;
    _Float16* BwD = BwE + wfrag;

    pack_wfrag<<<HID * HID / (256 * 8), 256, 0, stream>>>(enc_Whh, BwE);
    pack_wfrag<<<HID * HID / (256 * 8), 256, 0, stream>>>(dec_Whh, BwD);

    rnn_persist<<<NBLK, TPB, 0, stream>>>(
        x, BwE, BwD,
        enc_Wih, enc_bih, enc_bhh,
        dec_Wih, dec_bih, dec_bhh,
        fc_W, fc_b, out);
}